// Round 1
// 2098.549 us; speedup vs baseline: 1.8876x; 1.8876x over previous
//
#include <hip/hip_runtime.h>

#define BATCH 32
#define HGRID 24
#define WGRID 24
#define DIN   768
#define HID   384
#define GATES 1536
#define SEQT  24
#define NROWS (BATCH*HGRID*WGRID)   /* 18432 feature rows */
#define NSEQ  (BATCH*HGRID)         /* 768 sequences per direction-set */
#define SCH   6                     /* sequences per recurrence block */

typedef _Float16 f16x8 __attribute__((ext_vector_type(8)));
typedef _Float16 f16x4 __attribute__((ext_vector_type(4)));
typedef float    f32x4 __attribute__((ext_vector_type(4)));

struct WPtrs {
  const float* Wx[4];
  const float* Wh[4];
  const float* b[4];
};

__device__ __forceinline__ float fast_sigmoid(float x) {
  x = fminf(fmaxf(x, -30.f), 30.f);
  float e = __builtin_amdgcn_exp2f(-1.44269504f * x);
  return __builtin_amdgcn_rcpf(1.0f + e);
}
__device__ __forceinline__ float fast_tanh(float x) {
  x = fminf(fmaxf(x, -15.f), 15.f);
  float e = __builtin_amdgcn_exp2f(-2.88539008f * x);   /* e^(-2x) */
  return (1.0f - e) * __builtin_amdgcn_rcpf(1.0f + e);
}

/* bf16 RNE helpers (Wh2 packing for recur) */
__device__ __forceinline__ unsigned short bfr(float a) {
  unsigned u = __float_as_uint(a);
  u = (u + 0x7FFFu + ((u >> 16) & 1u)) >> 16;
  return (unsigned short)u;
}
__device__ __forceinline__ unsigned bpack(float a, float b) {
  return (unsigned)bfr(a) | ((unsigned)bfr(b) << 16);
}

/* async global->LDS, 16B per lane (LDS dest must be linear base + lane*16) */
__device__ __forceinline__ void gl16(const void* g, void* l) {
  __builtin_amdgcn_global_load_lds(
      (const __attribute__((address_space(1))) unsigned int*)g,
      (__attribute__((address_space(3))) unsigned int*)l, 16, 0, 0);
}

/* ---------------- Phase 0a: repack Wh -> bf16x4 per (k,q) ------------------ */
__global__ __launch_bounds__(256) void repack_wh(WPtrs P, uint2* __restrict__ Wh2) {
  const int idx = blockIdx.x * 256 + threadIdx.x;
  if (idx >= 4 * HID * HID) return;
  const int l = idx / (HID * HID);
  const int r = idx % (HID * HID);
  const int k = r / HID;
  const int q = r % HID;
  const float* row = P.Wh[l] + (size_t)k * GATES;
  uint2 o;
  o.x = bpack(row[q], row[384 + q]);
  o.y = bpack(row[768 + q], row[1152 + q]);
  Wh2[(size_t)l * HID * HID + (size_t)k * HID + q] = o;
}

/* ---------------- Phase 0b: X fp32 -> fp16 --------------------------------- */
__global__ __launch_bounds__(256) void cvt_x(const float* __restrict__ X,
                                             unsigned short* __restrict__ Xh_) {
  const size_t i = ((size_t)blockIdx.x * 256 + threadIdx.x) * 4;
  if (i >= (size_t)NROWS * DIN) return;
  const float4 v = *(const float4*)(X + i);
  f16x4 o = {(_Float16)v.x, (_Float16)v.y, (_Float16)v.z, (_Float16)v.w};
  *(f16x4*)((_Float16*)Xh_ + i) = o;
}

/* ---------------- Phase 0c: Wx fp32 [k][n] -> fp16 WxT [l][n][k] -----------
 * 32x32 LDS tile transpose so both global read and global write coalesce.
 * Gives k-contiguous rows so the MFMA B-fragment is one ds_read_b128. */
__global__ __launch_bounds__(256) void cvt_wx(WPtrs P, unsigned short* __restrict__ WxT_) {
  const int l  = blockIdx.z;
  const int n0 = blockIdx.x * 32;
  const int k0 = blockIdx.y * 32;
  const float* __restrict__ W = P.Wx[l];
  _Float16* __restrict__ WxT = (_Float16*)WxT_;
  __shared__ float T[32][33];
  const int t = threadIdx.x;
  {
    const int k = t >> 3, nc = (t & 7) * 4;
    const float4 v = *(const float4*)(W + (size_t)(k0 + k) * GATES + n0 + nc);
    T[k][nc] = v.x; T[k][nc + 1] = v.y; T[k][nc + 2] = v.z; T[k][nc + 3] = v.w;
  }
  __syncthreads();
  {
    const int n = t >> 3, kc = (t & 7) * 4;
    f16x4 o = {(_Float16)T[kc][n], (_Float16)T[kc + 1][n],
               (_Float16)T[kc + 2][n], (_Float16)T[kc + 3][n]};
    *(f16x4*)(WxT + ((size_t)l * GATES + n0 + n) * DIN + k0 + kc) = o;
  }
}

/* ---------------- Phase 1: Z = X @ Wx + b via fp16 MFMA --------------------
 * 128x128 tile, BK=32, 4 waves (2x2, 64x64 each), 16x16x32_f16, fp32 acc.
 * Both operands staged with global_load_lds width 16; LDS dest is linear,
 * the XOR bank-swizzle (chunk ^= (row>>1)&3 at 16B granularity) is applied
 * to the per-lane GLOBAL source address and again on the ds_read side
 * (both-sides-or-neither). Frag reads are then bank-optimal ds_read_b128.
 * Z stored as fp16 (finer than old bf16 -> offsets fp16 input rounding). */
__global__ __launch_bounds__(256) void gemm_zh(const unsigned short* __restrict__ Xh_,
                                               const unsigned short* __restrict__ WxT_,
                                               WPtrs P, int lbase,
                                               unsigned short* __restrict__ Z) {
  const _Float16* __restrict__ Xh = (const _Float16*)Xh_;
  const int bx = blockIdx.x;
  const int l_local = bx / 12;
  const int n0 = (bx % 12) * 128;
  const int m0 = blockIdx.y * 128;
  const _Float16* __restrict__ Wt =
      (const _Float16*)WxT_ + (size_t)(lbase + l_local) * GATES * DIN;
  const float* __restrict__ bias = P.b[lbase + l_local];
  unsigned short* __restrict__ Zl = Z + (size_t)l_local * NROWS * GATES;

  __shared__ _Float16 Ah[128 * 32];   /* [m][k] fp16, swizzled chunks, 8KB */
  __shared__ _Float16 Bh[128 * 32];   /* [n][k] fp16, swizzled chunks, 8KB */

  const int tid  = threadIdx.x;
  const int lane = tid & 63;
  const int wid  = tid >> 6;
  const int wm = (wid >> 1) * 64;
  const int wn = (wid & 1) * 64;

  f32x4 acc[4][4] = {};

  /* staging: linear LDS index L = p*256+tid -> row = p*64 + (tid>>2), chunk = tid&3
   * source chunk = chunk ^ sw(row); sw(row) = (row>>1)&3 (row mod 8 periodic,
   * so identical for row and row+64). */
  const int sr = tid >> 2;
  const int sc = tid & 3;
  const int sw0 = (sr >> 1) & 3;
  const _Float16* ag0 = Xh + (size_t)(m0 + sr) * DIN + (sc ^ sw0) * 8;
  const _Float16* ag1 = Xh + (size_t)(m0 + 64 + sr) * DIN + (sc ^ sw0) * 8;
  const _Float16* bg0 = Wt + (size_t)(n0 + sr) * DIN + (sc ^ sw0) * 8;
  const _Float16* bg1 = Wt + (size_t)(n0 + 64 + sr) * DIN + (sc ^ sw0) * 8;
  _Float16* la0 = Ah + tid * 8;
  _Float16* la1 = Ah + 2048 + tid * 8;
  _Float16* lb0 = Bh + tid * 8;
  _Float16* lb1 = Bh + 2048 + tid * 8;

  /* fragment read geometry: A row = lane&15 (+16*fa), k-group = lane>>4 */
  const int fr  = lane & 15;
  const int kg  = lane >> 4;
  const int swf = (fr >> 1) & 3;
  const int rchunk = (kg ^ swf) * 8;

  for (int k0 = 0; k0 < DIN; k0 += 32) {
    __syncthreads();                       /* all frag reads of prev tile done */
    gl16(ag0 + k0, la0);
    gl16(ag1 + k0, la1);
    gl16(bg0 + k0, lb0);
    gl16(bg1 + k0, lb1);
    __syncthreads();                       /* compiler drains vmcnt before barrier */

    f16x8 af[4], bf[4];
#pragma unroll
    for (int f = 0; f < 4; ++f) {
      const int row = wm + f * 16 + fr;
      af[f] = *(const f16x8*)&Ah[row * 32 + rchunk];
      const int col = wn + f * 16 + fr;
      bf[f] = *(const f16x8*)&Bh[col * 32 + rchunk];
    }
#pragma unroll
    for (int fa = 0; fa < 4; ++fa)
#pragma unroll
      for (int fb = 0; fb < 4; ++fb)
        acc[fa][fb] = __builtin_amdgcn_mfma_f32_16x16x32_f16(af[fa], bf[fb],
                                                             acc[fa][fb], 0, 0, 0);
  }

  /* epilogue: C/D layout col = lane&15, row = (lane>>4)*4 + r */
#pragma unroll
  for (int fb = 0; fb < 4; ++fb) {
    const int col = n0 + wn + fb * 16 + fr;
    const float bv = bias[col];
#pragma unroll
    for (int fa = 0; fa < 4; ++fa) {
#pragma unroll
      for (int r = 0; r < 4; ++r) {
        const int row = m0 + wm + fa * 16 + kg * 4 + r;
        _Float16 hv = (_Float16)(acc[fa][fb][r] + bv);
        Zl[(size_t)row * GATES + col] = *(const unsigned short*)&hv;
      }
    }
  }
}

/* ---------------- Phase 2: recurrence (unchanged except fp16 Z loads) ----- */
__global__ __launch_bounds__(384, 3) void recur(const unsigned short* __restrict__ Z,
                                                float* __restrict__ out,
                                                const uint2* __restrict__ Wh2,
                                                int lbase, int group) {
  const int bi = blockIdx.x;
  const int l_local = bi % group;       /* round-robin -> XCD L2 locality */
  const int chunk = bi / group;
  const int l = lbase + l_local;
  const uint2* __restrict__ Whl = Wh2 + (size_t)l * HID * HID;
  const unsigned short* __restrict__ Zl = Z + (size_t)l_local * NROWS * GATES;
  const int q = threadIdx.x;            /* hidden unit 0..383 */
  const int n0 = chunk * SCH;
  const bool rev = (l & 1);

  __shared__ float h_lds[2][HID * 8];   /* [buf][k*8 + s], 2 x 12 KB */

  float c[SCH];
#pragma unroll
  for (int s = 0; s < SCH; ++s) c[s] = 0.f;
#pragma unroll
  for (int s = 0; s < 8; ++s) h_lds[0][q * 8 + s] = 0.f;
  __syncthreads();

  /* feature-row r(s,t): horizontal r = n*24 + t ; vertical r = (n/24)*576 + t*24 + n%24 */
  int rbase[SCH];
  int rstep;
  if (l < 2) {
    rstep = 1;
#pragma unroll
    for (int s = 0; s < SCH; ++s) rbase[s] = (n0 + s) * SEQT;
  } else {
    rstep = 24;
#pragma unroll
    for (int s = 0; s < SCH; ++s) {
      const int n = n0 + s;
      rbase[s] = (n / 24) * 576 + (n % 24);
    }
  }

  /* Z prefetch registers: zn[gate][s] for the NEXT step */
  float zn[4][SCH];
  {
    const int t0 = rev ? (SEQT - 1) : 0;
#pragma unroll
    for (int s = 0; s < SCH; ++s) {
      const unsigned short* zrow = Zl + (size_t)(rbase[s] + t0 * rstep) * GATES;
      zn[0][s] = (float)(*(const _Float16*)(zrow + q));
      zn[1][s] = (float)(*(const _Float16*)(zrow + 384 + q));
      zn[2][s] = (float)(*(const _Float16*)(zrow + 768 + q));
      zn[3][s] = (float)(*(const _Float16*)(zrow + 1152 + q));
    }
  }

  int cur = 0;
  for (int it = 0; it < SEQT; ++it) {
    const int tt = rev ? (SEQT - 1 - it) : it;

    float gi[SCH], gf[SCH], gc[SCH], go[SCH];
#pragma unroll
    for (int s = 0; s < SCH; ++s) {
      gi[s] = zn[0][s]; gf[s] = zn[1][s];
      gc[s] = zn[2][s]; go[s] = zn[3][s];
    }

    /* issue next step's Z loads now; consumed only next iteration, so the
     * k-loop below hides their HBM latency */
    if (it + 1 < SEQT) {
      const int tn = rev ? (SEQT - 2 - it) : (it + 1);
#pragma unroll
      for (int s = 0; s < SCH; ++s) {
        const unsigned short* zrow = Zl + (size_t)(rbase[s] + tn * rstep) * GATES;
        zn[0][s] = (float)(*(const _Float16*)(zrow + q));
        zn[1][s] = (float)(*(const _Float16*)(zrow + 384 + q));
        zn[2][s] = (float)(*(const _Float16*)(zrow + 768 + q));
        zn[3][s] = (float)(*(const _Float16*)(zrow + 1152 + q));
      }
    }

    const uint2* wp = Whl + q;
    const float* hb = h_lds[cur];
#pragma unroll 8
    for (int k = 0; k < HID; ++k) {
      const uint2 w = wp[(size_t)k * HID];
      const float wi = __uint_as_float(w.x << 16);
      const float wf = __uint_as_float(w.x & 0xFFFF0000u);
      const float wc = __uint_as_float(w.y << 16);
      const float wo = __uint_as_float(w.y & 0xFFFF0000u);
      const float4 h0 = *(const float4*)&hb[k * 8];
      const float2 h1 = *(const float2*)&hb[k * 8 + 4];
      const float hv[SCH] = {h0.x, h0.y, h0.z, h0.w, h1.x, h1.y};
#pragma unroll
      for (int s = 0; s < SCH; ++s) {
        gi[s] = fmaf(hv[s], wi, gi[s]);
        gf[s] = fmaf(hv[s], wf, gf[s]);
        gc[s] = fmaf(hv[s], wc, gc[s]);
        go[s] = fmaf(hv[s], wo, go[s]);
      }
    }

    float* hn = h_lds[cur ^ 1];
#pragma unroll
    for (int s = 0; s < SCH; ++s) {
      const float ig = fast_sigmoid(gi[s]);
      const float fg = fast_sigmoid(gf[s]);
      const float cd = fast_tanh(gc[s]);
      const float og = fast_sigmoid(go[s]);
      const float cn = fmaf(fg, c[s], ig * cd);
      c[s] = cn;
      const float hv = og * fast_tanh(cn);
      hn[q * 8 + s] = hv;
      out[(size_t)(rbase[s] + tt * rstep) * GATES + l * HID + q] = hv;
    }
    __syncthreads();   /* new h visible before next step's GEMM reads */
    cur ^= 1;
  }
}

extern "C" void kernel_launch(void* const* d_in, const int* in_sizes, int n_in,
                              void* d_out, int out_size, void* d_ws, size_t ws_size,
                              hipStream_t stream) {
  const float* feat = (const float*)d_in[0];
  WPtrs P;
  P.Wx[0] = (const float*)d_in[1];  P.Wh[0] = (const float*)d_in[2];  P.b[0] = (const float*)d_in[3];
  P.Wx[1] = (const float*)d_in[4];  P.Wh[1] = (const float*)d_in[5];  P.b[1] = (const float*)d_in[6];
  P.Wx[2] = (const float*)d_in[7];  P.Wh[2] = (const float*)d_in[8];  P.b[2] = (const float*)d_in[9];
  P.Wx[3] = (const float*)d_in[10]; P.Wh[3] = (const float*)d_in[11]; P.b[3] = (const float*)d_in[12];
  float* out = (float*)d_out;
  unsigned short* Z = (unsigned short*)d_ws;

  const size_t slabB = (size_t)NROWS * GATES * sizeof(unsigned short); /* 56.6 MB fp16 Z slab */
  const size_t whB   = (size_t)4 * HID * HID * sizeof(uint2);          /* 4.72 MB packed Wh */
  const size_t xhB   = (size_t)NROWS * DIN * 2;                        /* 28.3 MB fp16 X */
  const size_t wxtB  = (size_t)4 * GATES * DIN * 2;                    /* 9.44 MB fp16 WxT */
  const size_t extras = whB + xhB + wxtB;
  const int group = (ws_size >= 4 * slabB + extras) ? 4
                  : (ws_size >= 2 * slabB + extras) ? 2 : 1;
  char* wp = (char*)d_ws + (size_t)group * slabB;
  uint2* Wh2            = (uint2*)wp;           wp += whB;
  unsigned short* Xh    = (unsigned short*)wp;  wp += xhB;
  unsigned short* WxT   = (unsigned short*)wp;

  repack_wh<<<(4 * HID * HID + 255) / 256, 256, 0, stream>>>(P, Wh2);
  cvt_x<<<(NROWS * DIN / 4 + 255) / 256, 256, 0, stream>>>(feat, Xh);
  cvt_wx<<<dim3(GATES / 32, DIN / 32, 4), 256, 0, stream>>>(P, WxT);

  for (int lbase = 0; lbase < 4; lbase += group) {
    gemm_zh<<<dim3(12 * group, NROWS / 128), 256, 0, stream>>>(Xh, WxT, P, lbase, Z);
    recur<<<dim3((NSEQ / SCH) * group), 384, 0, stream>>>(Z, out, Wh2, lbase, group);
  }
}

// Round 2
// 2010.547 us; speedup vs baseline: 1.9702x; 1.0438x over previous
//
#include <hip/hip_runtime.h>

#define BATCH 32
#define HGRID 24
#define WGRID 24
#define DIN   768
#define HID   384
#define GATES 1536
#define SEQT  24
#define NROWS (BATCH*HGRID*WGRID)   /* 18432 feature rows */
#define NSEQ  (BATCH*HGRID)         /* 768 sequences per direction-set */

typedef _Float16 f16x8 __attribute__((ext_vector_type(8)));
typedef _Float16 f16x4 __attribute__((ext_vector_type(4)));
typedef float    f32x4 __attribute__((ext_vector_type(4)));

struct WPtrs {
  const float* Wx[4];
  const float* Wh[4];
  const float* b[4];
};

__device__ __forceinline__ float fast_sigmoid(float x) {
  x = fminf(fmaxf(x, -30.f), 30.f);
  float e = __builtin_amdgcn_exp2f(-1.44269504f * x);
  return __builtin_amdgcn_rcpf(1.0f + e);
}
__device__ __forceinline__ float fast_tanh(float x) {
  x = fminf(fmaxf(x, -15.f), 15.f);
  float e = __builtin_amdgcn_exp2f(-2.88539008f * x);   /* e^(-2x) */
  return (1.0f - e) * __builtin_amdgcn_rcpf(1.0f + e);
}

/* async global->LDS, 16B per lane (LDS dest must be linear base + lane*16) */
__device__ __forceinline__ void gl16(const void* g, void* l) {
  __builtin_amdgcn_global_load_lds(
      (const __attribute__((address_space(1))) unsigned int*)g,
      (__attribute__((address_space(3))) unsigned int*)l, 16, 0, 0);
}

/* ---------------- Phase 0a: X fp32 -> fp16 --------------------------------- */
__global__ __launch_bounds__(256) void cvt_x(const float* __restrict__ X,
                                             unsigned short* __restrict__ Xh_) {
  const size_t i = ((size_t)blockIdx.x * 256 + threadIdx.x) * 4;
  if (i >= (size_t)NROWS * DIN) return;
  const float4 v = *(const float4*)(X + i);
  f16x4 o = {(_Float16)v.x, (_Float16)v.y, (_Float16)v.z, (_Float16)v.w};
  *(f16x4*)((_Float16*)Xh_ + i) = o;
}

/* ---------------- Phase 0b: Wx fp32 [k][n] -> fp16 WxT [l][n][k] ----------- */
__global__ __launch_bounds__(256) void cvt_wx(WPtrs P, unsigned short* __restrict__ WxT_) {
  const int l  = blockIdx.z;
  const int n0 = blockIdx.x * 32;
  const int k0 = blockIdx.y * 32;
  const float* __restrict__ W = P.Wx[l];
  _Float16* __restrict__ WxT = (_Float16*)WxT_;
  __shared__ float T[32][33];
  const int t = threadIdx.x;
  {
    const int k = t >> 3, nc = (t & 7) * 4;
    const float4 v = *(const float4*)(W + (size_t)(k0 + k) * GATES + n0 + nc);
    T[k][nc] = v.x; T[k][nc + 1] = v.y; T[k][nc + 2] = v.z; T[k][nc + 3] = v.w;
  }
  __syncthreads();
  {
    const int n = t >> 3, kc = (t & 7) * 4;
    f16x4 o = {(_Float16)T[kc][n], (_Float16)T[kc + 1][n],
               (_Float16)T[kc + 2][n], (_Float16)T[kc + 3][n]};
    *(f16x4*)(WxT + ((size_t)l * GATES + n0 + n) * DIN + k0 + kc) = o;
  }
}

/* ---------------- Phase 0c: Wh fp32 -> fp16 MFMA-fragment order ------------
 * Whf[((l*8 + w)*144 + p)*64 + lane][8] where p = kb*12 + nf,
 * value = Wh[l][k = kb*32 + (lane>>4)*8 + e][n = (w*12+nf)*16 + (lane&15)].
 * Lane loads its B-fragment as one linear dwordx4 in recur_mfma. */
__global__ __launch_bounds__(256) void repack_whf(WPtrs P, unsigned short* __restrict__ Whf_) {
  const int idx = blockIdx.x * 256 + threadIdx.x;
  if (idx >= 4 * 8 * 144 * 64) return;
  const int lane = idx & 63;
  int r = idx >> 6;
  const int p = r % 144; r /= 144;
  const int w = r % 8;
  const int l = r / 8;
  const int kb = p / 12, nfl = p % 12;
  const int n  = (w * 12 + nfl) * 16 + (lane & 15);
  const int k0 = kb * 32 + (lane >> 4) * 8;
  const float* src = P.Wh[l] + (size_t)k0 * GATES + n;
  f16x8 o;
#pragma unroll
  for (int e = 0; e < 8; ++e) o[e] = (_Float16)src[(size_t)e * GATES];
  *(f16x8*)((_Float16*)Whf_ + (size_t)idx * 8) = o;
}

/* ---------------- Phase 1: Z = X @ Wx + b via fp16 MFMA (unchanged) -------- */
__global__ __launch_bounds__(256) void gemm_zh(const unsigned short* __restrict__ Xh_,
                                               const unsigned short* __restrict__ WxT_,
                                               WPtrs P, int lbase,
                                               unsigned short* __restrict__ Z) {
  const _Float16* __restrict__ Xh = (const _Float16*)Xh_;
  const int bx = blockIdx.x;
  const int l_local = bx / 12;
  const int n0 = (bx % 12) * 128;
  const int m0 = blockIdx.y * 128;
  const _Float16* __restrict__ Wt =
      (const _Float16*)WxT_ + (size_t)(lbase + l_local) * GATES * DIN;
  const float* __restrict__ bias = P.b[lbase + l_local];
  unsigned short* __restrict__ Zl = Z + (size_t)l_local * NROWS * GATES;

  __shared__ _Float16 Ah[128 * 32];
  __shared__ _Float16 Bh[128 * 32];

  const int tid  = threadIdx.x;
  const int lane = tid & 63;
  const int wid  = tid >> 6;
  const int wm = (wid >> 1) * 64;
  const int wn = (wid & 1) * 64;

  f32x4 acc[4][4] = {};

  const int sr = tid >> 2;
  const int sc = tid & 3;
  const int sw0 = (sr >> 1) & 3;
  const _Float16* ag0 = Xh + (size_t)(m0 + sr) * DIN + (sc ^ sw0) * 8;
  const _Float16* ag1 = Xh + (size_t)(m0 + 64 + sr) * DIN + (sc ^ sw0) * 8;
  const _Float16* bg0 = Wt + (size_t)(n0 + sr) * DIN + (sc ^ sw0) * 8;
  const _Float16* bg1 = Wt + (size_t)(n0 + 64 + sr) * DIN + (sc ^ sw0) * 8;
  _Float16* la0 = Ah + tid * 8;
  _Float16* la1 = Ah + 2048 + tid * 8;
  _Float16* lb0 = Bh + tid * 8;
  _Float16* lb1 = Bh + 2048 + tid * 8;

  const int fr  = lane & 15;
  const int kg  = lane >> 4;
  const int swf = (fr >> 1) & 3;
  const int rchunk = (kg ^ swf) * 8;

  for (int k0 = 0; k0 < DIN; k0 += 32) {
    __syncthreads();
    gl16(ag0 + k0, la0);
    gl16(ag1 + k0, la1);
    gl16(bg0 + k0, lb0);
    gl16(bg1 + k0, lb1);
    __syncthreads();

    f16x8 af[4], bf[4];
#pragma unroll
    for (int f = 0; f < 4; ++f) {
      const int row = wm + f * 16 + fr;
      af[f] = *(const f16x8*)&Ah[row * 32 + rchunk];
      const int col = wn + f * 16 + fr;
      bf[f] = *(const f16x8*)&Bh[col * 32 + rchunk];
    }
#pragma unroll
    for (int fa = 0; fa < 4; ++fa)
#pragma unroll
      for (int fb = 0; fb < 4; ++fb)
        acc[fa][fb] = __builtin_amdgcn_mfma_f32_16x16x32_f16(af[fa], bf[fb],
                                                             acc[fa][fb], 0, 0, 0);
  }

#pragma unroll
  for (int fb = 0; fb < 4; ++fb) {
    const int col = n0 + wn + fb * 16 + fr;
    const float bv = bias[col];
#pragma unroll
    for (int fa = 0; fa < 4; ++fa) {
#pragma unroll
      for (int r = 0; r < 4; ++r) {
        const int row = m0 + wm + fa * 16 + kg * 4 + r;
        _Float16 hv = (_Float16)(acc[fa][fb][r] + bv);
        Zl[(size_t)row * GATES + col] = *(const unsigned short*)&hv;
      }
    }
  }
}

/* ---------------- Phase 2: recurrence via MFMA -----------------------------
 * Block = 16 sequences of one direction, 512 threads / 8 waves, 48*group
 * blocks.  Per step: G[16,1536] = h[16,384] @ Wh via mfma_f32_16x16x32_f16;
 * wave w owns cols w*192..w*192+191 (gate w>>1).  B streams global->reg in
 * frag order (Whf), 8-deep rolling buffer; h in swizzled LDS (A-frags);
 * gates exchanged through swizzled 98KB LDS; Z added + nonlinearity in the
 * elementwise phase (384 active threads: s=t&15, units (t>>4)*16..+15).
 * bid%8 -> XCD pinning keeps each direction's 1.18MB Whf slab L2-resident. */
__global__ __launch_bounds__(512, 2) void recur_mfma(
    const unsigned short* __restrict__ Z,
    float* __restrict__ out,
    const unsigned short* __restrict__ Whf_,
    int lbase, int group) {
  const int bid = blockIdx.x;
  const int xcd = bid & 7;
  const int xpd = 8 / group;                 /* XCDs per direction */
  const int dir_local = xcd / xpd;
  const int grp = (bid >> 3) * xpd + (xcd % xpd);   /* 0..47 */
  const int l = lbase + dir_local;
  const _Float16* __restrict__ Whl = (const _Float16*)Whf_ + (size_t)l * 8 * 144 * 512;
  const _Float16* __restrict__ Zl  = (const _Float16*)Z + (size_t)dir_local * NROWS * GATES;
  const int t = threadIdx.x;
  const int lane = t & 63;
  const int w = t >> 6;
  const bool rev = (l & 1);

  __shared__ float    Gs[4 * 16 * 96 * 4];   /* 98304 B, granule ^= (s&7) */
  __shared__ _Float16 hA[16 * 48 * 8];       /* 12288 B, granule ^= (r&7) */

  const int s  = t & 15;          /* phase-C seq (t<384) */
  const int u0 = (t >> 4) * 16;   /* phase-C unit base (t<384) */
  int rbase, rstep;
  {
    const int n = grp * 16 + s;
    if (l < 2) { rstep = 1;  rbase = n * 24; }
    else       { rstep = 24; rbase = (n / 24) * 576 + (n % 24); }
  }

  float c[16];
#pragma unroll
  for (int j = 0; j < 16; ++j) c[j] = 0.f;

  if (t < 384) {                  /* zero h(0): covers all 16x48 granules */
    const f16x8 zz = {};
#pragma unroll
    for (int i = 0; i < 2; ++i) {
      const int kg8 = (u0 >> 3) + i;
      *(f16x8*)&hA[((s * 48) + (kg8 ^ (s & 7))) * 8] = zz;
    }
  }
  __syncthreads();

  const _Float16* __restrict__ wbase = Whl + (size_t)w * 144 * 512 + lane * 8;
  const int fr = lane & 15;       /* A row / B col within frag */
  const int kq = lane >> 4;       /* k-quarter within frag */

  for (int it = 0; it < SEQT; ++it) {
    const int tt = rev ? (SEQT - 1 - it) : it;
    const int zrow = rbase + tt * rstep;

    /* Z prefetch: consumed in phase C, ~20k cycles later */
    f16x8 zr[4][2];
    if (t < 384) {
#pragma unroll
      for (int g = 0; g < 4; ++g)
#pragma unroll
        for (int h2 = 0; h2 < 2; ++h2)
          zr[g][h2] = *(const f16x8*)(Zl + (size_t)zrow * GATES + g * 384 + u0 + h2 * 8);
    }

    /* ---- phase A: MFMA sweep, B streamed from L2 ---- */
    f16x8 af[12];
#pragma unroll
    for (int kb = 0; kb < 12; ++kb) {
      const int cg = (kb * 4 + kq) ^ (fr & 7);
      af[kb] = *(const f16x8*)&hA[((fr * 48) + cg) * 8];
    }
    f32x4 acc[12];
#pragma unroll
    for (int nf = 0; nf < 12; ++nf) acc[nf] = (f32x4){0.f, 0.f, 0.f, 0.f};

    f16x8 bf[8];
#pragma unroll
    for (int j = 0; j < 8; ++j) bf[j] = *(const f16x8*)(wbase + (size_t)j * 512);
#pragma unroll
    for (int m = 0; m < 144; ++m) {          /* p = kb*12 + nf : kb-major */
      const int kb = m / 12, nf = m % 12;
      const f16x8 cur = bf[m & 7];
      if (m + 8 < 144) bf[m & 7] = *(const f16x8*)(wbase + (size_t)(m + 8) * 512);
      acc[nf] = __builtin_amdgcn_mfma_f32_16x16x32_f16(af[kb], cur, acc[nf], 0, 0, 0);
    }

    __syncthreads();    /* prev phase-C G reads done; hA reads done */

    /* ---- phase B: dump pre-activation gates to Gs ---- */
    {
      const int g  = w >> 1;
      const int ub = (w & 1) * 192;
#pragma unroll
      for (int nf = 0; nf < 12; ++nf) {
        const int u = ub + nf * 16 + fr;
#pragma unroll
        for (int r = 0; r < 4; ++r) {
          const int ss = kq * 4 + r;
          Gs[((g * 16 + ss) * 96 + ((u >> 2) ^ (ss & 7))) * 4 + (u & 3)] = acc[nf][r];
        }
      }
    }
    __syncthreads();

    /* ---- phase C: Z-add, nonlinearity, c/h update, stores ---- */
    if (t < 384) {
      float gv[4][16];
#pragma unroll
      for (int g = 0; g < 4; ++g) {
#pragma unroll
        for (int i = 0; i < 4; ++i) {
          const f32x4 v = *(const f32x4*)&Gs[((g * 16 + s) * 96 +
                                              (((u0 >> 2) + i) ^ (s & 7))) * 4];
#pragma unroll
          for (int e = 0; e < 4; ++e) gv[g][i * 4 + e] = v[e];
        }
      }
      float hv[16];
#pragma unroll
      for (int j = 0; j < 16; ++j) {
        const float ig = fast_sigmoid(gv[0][j] + (float)zr[0][j >> 3][j & 7]);
        const float fg = fast_sigmoid(gv[1][j] + (float)zr[1][j >> 3][j & 7]);
        const float cd = fast_tanh  (gv[2][j] + (float)zr[2][j >> 3][j & 7]);
        const float og = fast_sigmoid(gv[3][j] + (float)zr[3][j >> 3][j & 7]);
        const float cn = fmaf(fg, c[j], ig * cd);
        c[j] = cn;
        hv[j] = og * fast_tanh(cn);
      }
      float* orow = out + (size_t)zrow * GATES + l * HID + u0;
#pragma unroll
      for (int i = 0; i < 4; ++i) {
        f32x4 v = {hv[i * 4], hv[i * 4 + 1], hv[i * 4 + 2], hv[i * 4 + 3]};
        *(f32x4*)(orow + i * 4) = v;
      }
#pragma unroll
      for (int i = 0; i < 2; ++i) {
        f16x8 hh;
#pragma unroll
        for (int e = 0; e < 8; ++e) hh[e] = (_Float16)hv[i * 8 + e];
        const int kg8 = (u0 >> 3) + i;
        *(f16x8*)&hA[((s * 48) + (kg8 ^ (s & 7))) * 8] = hh;
      }
    }
    __syncthreads();    /* new h visible before next step's MFMA */
  }
}

extern "C" void kernel_launch(void* const* d_in, const int* in_sizes, int n_in,
                              void* d_out, int out_size, void* d_ws, size_t ws_size,
                              hipStream_t stream) {
  const float* feat = (const float*)d_in[0];
  WPtrs P;
  P.Wx[0] = (const float*)d_in[1];  P.Wh[0] = (const float*)d_in[2];  P.b[0] = (const float*)d_in[3];
  P.Wx[1] = (const float*)d_in[4];  P.Wh[1] = (const float*)d_in[5];  P.b[1] = (const float*)d_in[6];
  P.Wx[2] = (const float*)d_in[7];  P.Wh[2] = (const float*)d_in[8];  P.b[2] = (const float*)d_in[9];
  P.Wx[3] = (const float*)d_in[10]; P.Wh[3] = (const float*)d_in[11]; P.b[3] = (const float*)d_in[12];
  float* out = (float*)d_out;
  unsigned short* Z = (unsigned short*)d_ws;

  const size_t slabB = (size_t)NROWS * GATES * sizeof(unsigned short); /* 56.6 MB fp16 Z slab */
  const size_t xhB   = (size_t)NROWS * DIN * 2;                        /* 28.3 MB fp16 X */
  const size_t wxtB  = (size_t)4 * GATES * DIN * 2;                    /* 9.44 MB fp16 WxT */
  const size_t whfB  = (size_t)4 * 8 * 144 * 64 * 8 * 2;               /* 4.72 MB fp16 Whf */
  const size_t extras = xhB + wxtB + whfB;
  const int group = (ws_size >= 4 * slabB + extras) ? 4
                  : (ws_size >= 2 * slabB + extras) ? 2 : 1;
  char* wp = (char*)d_ws + (size_t)group * slabB;
  unsigned short* Xh  = (unsigned short*)wp;  wp += xhB;
  unsigned short* WxT = (unsigned short*)wp;  wp += wxtB;
  unsigned short* Whf = (unsigned short*)wp;

  cvt_x<<<(NROWS * DIN / 4 + 255) / 256, 256, 0, stream>>>(feat, Xh);
  cvt_wx<<<dim3(GATES / 32, DIN / 32, 4), 256, 0, stream>>>(P, WxT);
  repack_whf<<<(4 * 8 * 144 * 64 + 255) / 256, 256, 0, stream>>>(P, Whf);

  for (int lbase = 0; lbase < 4; lbase += group) {
    gemm_zh<<<dim3(12 * group, NROWS / 128), 256, 0, stream>>>(Xh, WxT, P, lbase, Z);
    recur_mfma<<<dim3(48 * group), 512, 0, stream>>>(Z, out, Whf, lbase, group);
  }
}

// Round 3
// 1716.347 us; speedup vs baseline: 2.3080x; 1.1714x over previous
//
#include <hip/hip_runtime.h>

#define BATCH 32
#define HGRID 24
#define WGRID 24
#define DIN   768
#define HID   384
#define GATES 1536
#define SEQT  24
#define NROWS (BATCH*HGRID*WGRID)   /* 18432 feature rows */
#define NSEQ  (BATCH*HGRID)         /* 768 sequences per direction-set */

typedef _Float16 f16x8 __attribute__((ext_vector_type(8)));
typedef _Float16 f16x4 __attribute__((ext_vector_type(4)));
typedef float    f32x4 __attribute__((ext_vector_type(4)));

struct WPtrs {
  const float* Wx[4];
  const float* Wh[4];
  const float* b[4];
};

__device__ __forceinline__ float fast_sigmoid(float x) {
  x = fminf(fmaxf(x, -30.f), 30.f);
  float e = __builtin_amdgcn_exp2f(-1.44269504f * x);
  return __builtin_amdgcn_rcpf(1.0f + e);
}
__device__ __forceinline__ float fast_tanh(float x) {
  x = fminf(fmaxf(x, -15.f), 15.f);
  float e = __builtin_amdgcn_exp2f(-2.88539008f * x);   /* e^(-2x) */
  return (1.0f - e) * __builtin_amdgcn_rcpf(1.0f + e);
}

/* async global->LDS, 16B per lane (LDS dest must be linear base + lane*16) */
__device__ __forceinline__ void gl16(const void* g, void* l) {
  __builtin_amdgcn_global_load_lds(
      (const __attribute__((address_space(1))) unsigned int*)g,
      (__attribute__((address_space(3))) unsigned int*)l, 16, 0, 0);
}

/* ---------------- Phase 0a: X fp32 -> fp16 --------------------------------- */
__global__ __launch_bounds__(256) void cvt_x(const float* __restrict__ X,
                                             unsigned short* __restrict__ Xh_) {
  const size_t i = ((size_t)blockIdx.x * 256 + threadIdx.x) * 4;
  if (i >= (size_t)NROWS * DIN) return;
  const float4 v = *(const float4*)(X + i);
  f16x4 o = {(_Float16)v.x, (_Float16)v.y, (_Float16)v.z, (_Float16)v.w};
  *(f16x4*)((_Float16*)Xh_ + i) = o;
}

/* ---------------- Phase 0b: Wx fp32 [k][n] -> fp16 WxT [l][n][k] ----------- */
__global__ __launch_bounds__(256) void cvt_wx(WPtrs P, unsigned short* __restrict__ WxT_) {
  const int l  = blockIdx.z;
  const int n0 = blockIdx.x * 32;
  const int k0 = blockIdx.y * 32;
  const float* __restrict__ W = P.Wx[l];
  _Float16* __restrict__ WxT = (_Float16*)WxT_;
  __shared__ float T[32][33];
  const int t = threadIdx.x;
  {
    const int k = t >> 3, nc = (t & 7) * 4;
    const float4 v = *(const float4*)(W + (size_t)(k0 + k) * GATES + n0 + nc);
    T[k][nc] = v.x; T[k][nc + 1] = v.y; T[k][nc + 2] = v.z; T[k][nc + 3] = v.w;
  }
  __syncthreads();
  {
    const int n = t >> 3, kc = (t & 7) * 4;
    f16x4 o = {(_Float16)T[kc][n], (_Float16)T[kc + 1][n],
               (_Float16)T[kc + 2][n], (_Float16)T[kc + 3][n]};
    *(f16x4*)(WxT + ((size_t)l * GATES + n0 + n) * DIN + k0 + kc) = o;
  }
}

/* ---------------- Phase 0c: Wh fp32 -> fp16 MFMA-fragment order ------------
 * Whf[((l*8 + w)*144 + p)*64 + lane][8],  p = kb*12 + nf,  nf = g*3 + uf.
 * value = Wh[l][k = kb*32 + (lane>>4)*8 + e][n = g*384 + w*48 + uf*16 + (lane&15)]
 * Wave w owns units [w*48, w*48+48) x all 4 gates -> after MFMA every lane
 * holds i,f,c,o of its own (seq,unit) pairs in registers (no LDS exchange). */
__global__ __launch_bounds__(256) void repack_whf(WPtrs P, unsigned short* __restrict__ Whf_) {
  const int idx = blockIdx.x * 256 + threadIdx.x;
  if (idx >= 4 * 8 * 144 * 64) return;
  const int lane = idx & 63;
  int r = idx >> 6;
  const int p = r % 144; r /= 144;
  const int w = r % 8;
  const int l = r / 8;
  const int kb = p / 12, nfl = p % 12;
  const int g  = nfl / 3, uf = nfl % 3;
  const int n  = g * 384 + w * 48 + uf * 16 + (lane & 15);
  const int k0 = kb * 32 + (lane >> 4) * 8;
  const float* src = P.Wh[l] + (size_t)k0 * GATES + n;
  f16x8 o;
#pragma unroll
  for (int e = 0; e < 8; ++e) o[e] = (_Float16)src[(size_t)e * GATES];
  *(f16x8*)((_Float16*)Whf_ + (size_t)idx * 8) = o;
}

/* ---------------- Phase 1: Z = X @ Wx + b via fp16 MFMA (unchanged) -------- */
__global__ __launch_bounds__(256) void gemm_zh(const unsigned short* __restrict__ Xh_,
                                               const unsigned short* __restrict__ WxT_,
                                               WPtrs P, int lbase,
                                               unsigned short* __restrict__ Z) {
  const _Float16* __restrict__ Xh = (const _Float16*)Xh_;
  const int bx = blockIdx.x;
  const int l_local = bx / 12;
  const int n0 = (bx % 12) * 128;
  const int m0 = blockIdx.y * 128;
  const _Float16* __restrict__ Wt =
      (const _Float16*)WxT_ + (size_t)(lbase + l_local) * GATES * DIN;
  const float* __restrict__ bias = P.b[lbase + l_local];
  unsigned short* __restrict__ Zl = Z + (size_t)l_local * NROWS * GATES;

  __shared__ _Float16 Ah[128 * 32];
  __shared__ _Float16 Bh[128 * 32];

  const int tid  = threadIdx.x;
  const int lane = tid & 63;
  const int wid  = tid >> 6;
  const int wm = (wid >> 1) * 64;
  const int wn = (wid & 1) * 64;

  f32x4 acc[4][4] = {};

  const int sr = tid >> 2;
  const int sc = tid & 3;
  const int sw0 = (sr >> 1) & 3;
  const _Float16* ag0 = Xh + (size_t)(m0 + sr) * DIN + (sc ^ sw0) * 8;
  const _Float16* ag1 = Xh + (size_t)(m0 + 64 + sr) * DIN + (sc ^ sw0) * 8;
  const _Float16* bg0 = Wt + (size_t)(n0 + sr) * DIN + (sc ^ sw0) * 8;
  const _Float16* bg1 = Wt + (size_t)(n0 + 64 + sr) * DIN + (sc ^ sw0) * 8;
  _Float16* la0 = Ah + tid * 8;
  _Float16* la1 = Ah + 2048 + tid * 8;
  _Float16* lb0 = Bh + tid * 8;
  _Float16* lb1 = Bh + 2048 + tid * 8;

  const int fr  = lane & 15;
  const int kg  = lane >> 4;
  const int swf = (fr >> 1) & 3;
  const int rchunk = (kg ^ swf) * 8;

  for (int k0 = 0; k0 < DIN; k0 += 32) {
    __syncthreads();
    gl16(ag0 + k0, la0);
    gl16(ag1 + k0, la1);
    gl16(bg0 + k0, lb0);
    gl16(bg1 + k0, lb1);
    __syncthreads();

    f16x8 af[4], bf[4];
#pragma unroll
    for (int f = 0; f < 4; ++f) {
      const int row = wm + f * 16 + fr;
      af[f] = *(const f16x8*)&Ah[row * 32 + rchunk];
      const int col = wn + f * 16 + fr;
      bf[f] = *(const f16x8*)&Bh[col * 32 + rchunk];
    }
#pragma unroll
    for (int fa = 0; fa < 4; ++fa)
#pragma unroll
      for (int fb = 0; fb < 4; ++fb)
        acc[fa][fb] = __builtin_amdgcn_mfma_f32_16x16x32_f16(af[fa], bf[fb],
                                                             acc[fa][fb], 0, 0, 0);
  }

#pragma unroll
  for (int fb = 0; fb < 4; ++fb) {
    const int col = n0 + wn + fb * 16 + fr;
    const float bv = bias[col];
#pragma unroll
    for (int fa = 0; fa < 4; ++fa) {
#pragma unroll
      for (int r = 0; r < 4; ++r) {
        const int row = m0 + wm + fa * 16 + kg * 4 + r;
        _Float16 hv = (_Float16)(acc[fa][fb][r] + bv);
        Zl[(size_t)row * GATES + col] = *(const unsigned short*)&hv;
      }
    }
  }
}

/* ---------------- Phase 2: recurrence via MFMA, v2 -------------------------
 * Block = 32 seqs of one direction, 512 thr / 8 waves, 24*group blocks
 * (12/XCD).  Per step: G[32,1536] = h[32,384] @ Wh; wave w owns 48 units x
 * 4 gates (gate-interleaved Whf) so the epilogue is pure-register: each
 * lane holds acc rows {mf*16+kq*4+r}, units {w*48+uf*16+fr}.  No G LDS
 * exchange; 1 barrier/step; h double-buffered in swizzled LDS (48 KB).
 * Z loads + out stores are NON-TEMPORAL so the 1.18 MB/dir weight slab
 * stays L2-resident (this was the 2.49 GB HBM re-fetch).  it=0 skips the
 * sweep (h=0). */
__global__ __launch_bounds__(512, 2) void recur_mfma(
    const unsigned short* __restrict__ Z,
    float* __restrict__ out,
    const unsigned short* __restrict__ Whf_,
    int lbase, int group) {
  const int bid = blockIdx.x;
  const int xcd = bid & 7;
  const int xpd = 8 / group;                 /* XCDs per direction */
  const int dir_local = xcd / xpd;
  const int grp = (bid >> 3) * xpd + (xcd % xpd);   /* 0..23 */
  const int l = lbase + dir_local;
  const _Float16* __restrict__ Whl = (const _Float16*)Whf_ + (size_t)l * 8 * 144 * 512;
  const _Float16* __restrict__ Zl  = (const _Float16*)Z + (size_t)dir_local * NROWS * GATES;
  const int t = threadIdx.x;
  const int lane = t & 63;
  const int w = t >> 6;
  const bool rev = (l & 1);
  const int fr = lane & 15;       /* frag row/col */
  const int kq = lane >> 4;       /* k-quarter / C row-quarter */

  __shared__ _Float16 hA[2][32 * 384];   /* 2 x 24 KB, granule ^= (row&7) */

  /* zero h(0): 1536 granules of 16B, 3 per thread */
  {
    const f16x8 zz = {};
#pragma unroll
    for (int i = 0; i < 3; ++i) *(f16x8*)&hA[0][(t * 3 + i) * 8] = zz;
  }

  /* per-lane row bases: i = mf*4 + r -> seq n = grp*32 + mf*16 + kq*4 + r */
  int rbase8[8];
  int rstep = (l < 2) ? 1 : 24;
#pragma unroll
  for (int i = 0; i < 8; ++i) {
    const int n = grp * 32 + (i >> 2) * 16 + kq * 4 + (i & 3);
    rbase8[i] = (l < 2) ? n * 24 : (n / 24) * 576 + (n % 24);
  }

  float c[24];
#pragma unroll
  for (int j = 0; j < 24; ++j) c[j] = 0.f;

  const _Float16* __restrict__ wbase = Whl + (size_t)w * 144 * 512 + lane * 8;
  const int ubase = w * 48;

  __syncthreads();

  int cur = 0;
  for (int it = 0; it < SEQT; ++it) {
    const int tt = rev ? (SEQT - 1 - it) : it;

    /* prefetch Z for mf=0 rows (consumed in epilogue, hidden by sweep) */
    _Float16 z0[48];
#pragma unroll
    for (int g = 0; g < 4; ++g)
#pragma unroll
      for (int uf = 0; uf < 3; ++uf)
#pragma unroll
        for (int r = 0; r < 4; ++r)
          z0[(g * 3 + uf) * 4 + r] = __builtin_nontemporal_load(
              Zl + (size_t)(rbase8[r] + tt * rstep) * GATES +
              g * 384 + ubase + uf * 16 + fr);

    f32x4 acc0[12] = {}, acc1[12] = {};

    if (it) {   /* h==0 at it==0: sweep contributes nothing */
      const _Float16* hbuf = hA[cur];
      f16x8 bf[8];
#pragma unroll
      for (int j = 0; j < 8; ++j) bf[j] = *(const f16x8*)(wbase + (size_t)j * 512);
#pragma unroll
      for (int kb = 0; kb < 12; ++kb) {
        const int cg = ((kb * 4 + kq) ^ (fr & 7)) * 8;
        const f16x8 a0 = *(const f16x8*)&hbuf[(fr) * 384 + cg];
        const f16x8 a1 = *(const f16x8*)&hbuf[(16 + fr) * 384 + cg];
#pragma unroll
        for (int nf = 0; nf < 12; ++nf) {
          const int m = kb * 12 + nf;
          const f16x8 cb = bf[m & 7];
          if (m + 8 < 144) bf[m & 7] = *(const f16x8*)(wbase + (size_t)(m + 8) * 512);
          acc0[nf] = __builtin_amdgcn_mfma_f32_16x16x32_f16(a0, cb, acc0[nf], 0, 0, 0);
          acc1[nf] = __builtin_amdgcn_mfma_f32_16x16x32_f16(a1, cb, acc1[nf], 0, 0, 0);
        }
      }
    }

    /* issue Z loads for mf=1 rows; mf=0 compute hides their latency */
    _Float16 z1[48];
#pragma unroll
    for (int g = 0; g < 4; ++g)
#pragma unroll
      for (int uf = 0; uf < 3; ++uf)
#pragma unroll
        for (int r = 0; r < 4; ++r)
          z1[(g * 3 + uf) * 4 + r] = __builtin_nontemporal_load(
              Zl + (size_t)(rbase8[4 + r] + tt * rstep) * GATES +
              g * 384 + ubase + uf * 16 + fr);

    _Float16* hnxt = hA[cur ^ 1];

    /* ---- epilogue mf=0 ---- */
#pragma unroll
    for (int uf = 0; uf < 3; ++uf) {
      const int u = ubase + uf * 16 + fr;
      const int ug = (((u >> 3)) /*granule*/);
#pragma unroll
      for (int r = 0; r < 4; ++r) {
        const int zrow = rbase8[r] + tt * rstep;
        const float ig = fast_sigmoid(acc0[0 + uf][r] + (float)z0[(0 + uf) * 4 + r]);
        const float fg = fast_sigmoid(acc0[3 + uf][r] + (float)z0[(3 + uf) * 4 + r]);
        const float cd = fast_tanh  (acc0[6 + uf][r] + (float)z0[(6 + uf) * 4 + r]);
        const float og = fast_sigmoid(acc0[9 + uf][r] + (float)z0[(9 + uf) * 4 + r]);
        const float cn = fmaf(fg, c[uf * 4 + r], ig * cd);
        c[uf * 4 + r] = cn;
        const float hv = og * fast_tanh(cn);
        const int rr = kq * 4 + r;
        hnxt[rr * 384 + ((ug ^ (rr & 7)) * 8) + (u & 7)] = (_Float16)hv;
        __builtin_nontemporal_store(hv, out + (size_t)zrow * GATES + l * HID + u);
      }
    }
    /* ---- epilogue mf=1 ---- */
#pragma unroll
    for (int uf = 0; uf < 3; ++uf) {
      const int u = ubase + uf * 16 + fr;
      const int ug = (u >> 3);
#pragma unroll
      for (int r = 0; r < 4; ++r) {
        const int zrow = rbase8[4 + r] + tt * rstep;
        const float ig = fast_sigmoid(acc1[0 + uf][r] + (float)z1[(0 + uf) * 4 + r]);
        const float fg = fast_sigmoid(acc1[3 + uf][r] + (float)z1[(3 + uf) * 4 + r]);
        const float cd = fast_tanh  (acc1[6 + uf][r] + (float)z1[(6 + uf) * 4 + r]);
        const float og = fast_sigmoid(acc1[9 + uf][r] + (float)z1[(9 + uf) * 4 + r]);
        const float cn = fmaf(fg, c[12 + uf * 4 + r], ig * cd);
        c[12 + uf * 4 + r] = cn;
        const float hv = og * fast_tanh(cn);
        const int rr = 16 + kq * 4 + r;
        hnxt[rr * 384 + ((ug ^ (rr & 7)) * 8) + (u & 7)] = (_Float16)hv;
        __builtin_nontemporal_store(hv, out + (size_t)zrow * GATES + l * HID + u);
      }
    }

    __syncthreads();   /* new h visible before next step's sweep */
    cur ^= 1;
  }
}

extern "C" void kernel_launch(void* const* d_in, const int* in_sizes, int n_in,
                              void* d_out, int out_size, void* d_ws, size_t ws_size,
                              hipStream_t stream) {
  const float* feat = (const float*)d_in[0];
  WPtrs P;
  P.Wx[0] = (const float*)d_in[1];  P.Wh[0] = (const float*)d_in[2];  P.b[0] = (const float*)d_in[3];
  P.Wx[1] = (const float*)d_in[4];  P.Wh[1] = (const float*)d_in[5];  P.b[1] = (const float*)d_in[6];
  P.Wx[2] = (const float*)d_in[7];  P.Wh[2] = (const float*)d_in[8];  P.b[2] = (const float*)d_in[9];
  P.Wx[3] = (const float*)d_in[10]; P.Wh[3] = (const float*)d_in[11]; P.b[3] = (const float*)d_in[12];
  float* out = (float*)d_out;
  unsigned short* Z = (unsigned short*)d_ws;

  const size_t slabB = (size_t)NROWS * GATES * sizeof(unsigned short); /* 56.6 MB fp16 Z slab */
  const size_t xhB   = (size_t)NROWS * DIN * 2;                        /* 28.3 MB fp16 X */
  const size_t wxtB  = (size_t)4 * GATES * DIN * 2;                    /* 9.44 MB fp16 WxT */
  const size_t whfB  = (size_t)4 * 8 * 144 * 64 * 8 * 2;               /* 4.72 MB fp16 Whf */
  const size_t extras = xhB + wxtB + whfB;
  const int group = (ws_size >= 4 * slabB + extras) ? 4
                  : (ws_size >= 2 * slabB + extras) ? 2 : 1;
  char* wp = (char*)d_ws + (size_t)group * slabB;
  unsigned short* Xh  = (unsigned short*)wp;  wp += xhB;
  unsigned short* WxT = (unsigned short*)wp;  wp += wxtB;
  unsigned short* Whf = (unsigned short*)wp;

  cvt_x<<<(NROWS * DIN / 4 + 255) / 256, 256, 0, stream>>>(feat, Xh);
  cvt_wx<<<dim3(GATES / 32, DIN / 32, 4), 256, 0, stream>>>(P, WxT);
  repack_whf<<<(4 * 8 * 144 * 64 + 255) / 256, 256, 0, stream>>>(P, Whf);

  for (int lbase = 0; lbase < 4; lbase += group) {
    gemm_zh<<<dim3(12 * group, NROWS / 128), 256, 0, stream>>>(Xh, WxT, P, lbase, Z);
    recur_mfma<<<dim3(24 * group), 512, 0, stream>>>(Z, out, Whf, lbase, group);
  }
}

// Round 5
// 998.365 us; speedup vs baseline: 3.9677x; 1.7192x over previous
//
#include <hip/hip_runtime.h>

#define BATCH 32
#define HGRID 24
#define WGRID 24
#define DIN   768
#define HID   384
#define GATES 1536
#define SEQT  24
#define NROWS (BATCH*HGRID*WGRID)   /* 18432 feature rows */
#define NSEQ  (BATCH*HGRID)         /* 768 sequences per direction-set */

typedef _Float16 f16x8 __attribute__((ext_vector_type(8)));
typedef _Float16 f16x4 __attribute__((ext_vector_type(4)));
typedef float    f32x4 __attribute__((ext_vector_type(4)));

struct WPtrs {
  const float* Wx[4];
  const float* Wh[4];
  const float* b[4];
};

__device__ __forceinline__ float fast_sigmoid(float x) {
  x = fminf(fmaxf(x, -30.f), 30.f);
  float e = __builtin_amdgcn_exp2f(-1.44269504f * x);
  return __builtin_amdgcn_rcpf(1.0f + e);
}
__device__ __forceinline__ float fast_tanh(float x) {
  x = fminf(fmaxf(x, -15.f), 15.f);
  float e = __builtin_amdgcn_exp2f(-2.88539008f * x);   /* e^(-2x) */
  return (1.0f - e) * __builtin_amdgcn_rcpf(1.0f + e);
}

/* async global->LDS, 16B per lane (LDS dest = wave base + lane*16, linear) */
__device__ __forceinline__ void gl16(const void* g, void* l) {
  __builtin_amdgcn_global_load_lds(
      (const __attribute__((address_space(1))) unsigned int*)g,
      (__attribute__((address_space(3))) unsigned int*)l, 16, 0, 0);
}

/* ---------------- Phase 0a: X fp32 -> fp16 --------------------------------- */
__global__ __launch_bounds__(256) void cvt_x(const float* __restrict__ X,
                                             unsigned short* __restrict__ Xh_) {
  const size_t i = ((size_t)blockIdx.x * 256 + threadIdx.x) * 4;
  if (i >= (size_t)NROWS * DIN) return;
  const float4 v = *(const float4*)(X + i);
  f16x4 o = {(_Float16)v.x, (_Float16)v.y, (_Float16)v.z, (_Float16)v.w};
  *(f16x4*)((_Float16*)Xh_ + i) = o;
}

/* ---------------- Phase 0b: Wx fp32 [k][n] -> fp16 WxT [l][n][k] ----------- */
__global__ __launch_bounds__(256) void cvt_wx(WPtrs P, unsigned short* __restrict__ WxT_) {
  const int l  = blockIdx.z;
  const int n0 = blockIdx.x * 32;
  const int k0 = blockIdx.y * 32;
  const float* __restrict__ W = P.Wx[l];
  _Float16* __restrict__ WxT = (_Float16*)WxT_;
  __shared__ float T[32][33];
  const int t = threadIdx.x;
  {
    const int k = t >> 3, nc = (t & 7) * 4;
    const float4 v = *(const float4*)(W + (size_t)(k0 + k) * GATES + n0 + nc);
    T[k][nc] = v.x; T[k][nc + 1] = v.y; T[k][nc + 2] = v.z; T[k][nc + 3] = v.w;
  }
  __syncthreads();
  {
    const int n = t >> 3, kc = (t & 7) * 4;
    f16x4 o = {(_Float16)T[kc][n], (_Float16)T[kc + 1][n],
               (_Float16)T[kc + 2][n], (_Float16)T[kc + 3][n]};
    *(f16x4*)(WxT + ((size_t)l * GATES + n0 + n) * DIN + k0 + kc) = o;
  }
}

/* ---------------- Phase 0c: Wh fp32 -> fp16 slab-fragment order ------------
 * Slab (l,ug): 16 units (uu = ug*16 + fr) x 4 gates x K=384.  49152 B.
 * Whg[((l*24+ug)*48 + fi)*64 + lane][8],  fi = g*12 + kb,
 * value = Wh[l][k = kb*32 + (lane>>4)*8 + e][n = g*384 + ug*16 + (lane&15)]
 * recur_step stages one slab LINEARLY into LDS via global_load_lds; every
 * B-fragment is then a conflict-free ds_read_b128 (lane-contiguous 16B). */
__global__ __launch_bounds__(256) void repack_whg(WPtrs P, unsigned short* __restrict__ Whg_) {
  const int idx = blockIdx.x * 256 + threadIdx.x;
  if (idx >= 4 * 24 * 48 * 64) return;
  const int lane = idx & 63;
  int r = idx >> 6;
  const int fi = r % 48; r /= 48;
  const int ug = r % 24;
  const int l  = r / 24;
  const int g  = fi / 12;
  const int kb = fi % 12;
  const int n  = g * 384 + ug * 16 + (lane & 15);
  const int k0 = kb * 32 + (lane >> 4) * 8;
  const float* src = P.Wh[l] + (size_t)k0 * GATES + n;
  f16x8 o;
#pragma unroll
  for (int e = 0; e < 8; ++e) o[e] = (_Float16)src[(size_t)e * GATES];
  *(f16x8*)((_Float16*)Whg_ + (size_t)idx * 8) = o;
}

/* ---------------- Phase 1: Z = X @ Wx + b via fp16 MFMA (unchanged) -------- */
__global__ __launch_bounds__(256) void gemm_zh(const unsigned short* __restrict__ Xh_,
                                               const unsigned short* __restrict__ WxT_,
                                               WPtrs P, int lbase,
                                               unsigned short* __restrict__ Z) {
  const _Float16* __restrict__ Xh = (const _Float16*)Xh_;
  const int bx = blockIdx.x;
  const int l_local = bx / 12;
  const int n0 = (bx % 12) * 128;
  const int m0 = blockIdx.y * 128;
  const _Float16* __restrict__ Wt =
      (const _Float16*)WxT_ + (size_t)(lbase + l_local) * GATES * DIN;
  const float* __restrict__ bias = P.b[lbase + l_local];
  unsigned short* __restrict__ Zl = Z + (size_t)l_local * NROWS * GATES;

  __shared__ _Float16 Ah[128 * 32];
  __shared__ _Float16 Bh[128 * 32];

  const int tid  = threadIdx.x;
  const int lane = tid & 63;
  const int wid  = tid >> 6;
  const int wm = (wid >> 1) * 64;
  const int wn = (wid & 1) * 64;

  f32x4 acc[4][4] = {};

  const int sr = tid >> 2;
  const int sc = tid & 3;
  const int sw0 = (sr >> 1) & 3;
  const _Float16* ag0 = Xh + (size_t)(m0 + sr) * DIN + (sc ^ sw0) * 8;
  const _Float16* ag1 = Xh + (size_t)(m0 + 64 + sr) * DIN + (sc ^ sw0) * 8;
  const _Float16* bg0 = Wt + (size_t)(n0 + sr) * DIN + (sc ^ sw0) * 8;
  const _Float16* bg1 = Wt + (size_t)(n0 + 64 + sr) * DIN + (sc ^ sw0) * 8;
  _Float16* la0 = Ah + tid * 8;
  _Float16* la1 = Ah + 2048 + tid * 8;
  _Float16* lb0 = Bh + tid * 8;
  _Float16* lb1 = Bh + 2048 + tid * 8;

  const int fr  = lane & 15;
  const int kg  = lane >> 4;
  const int swf = (fr >> 1) & 3;
  const int rchunk = (kg ^ swf) * 8;

  for (int k0 = 0; k0 < DIN; k0 += 32) {
    __syncthreads();
    gl16(ag0 + k0, la0);
    gl16(ag1 + k0, la1);
    gl16(bg0 + k0, lb0);
    gl16(bg1 + k0, lb1);
    __syncthreads();

    f16x8 af[4], bf[4];
#pragma unroll
    for (int f = 0; f < 4; ++f) {
      const int row = wm + f * 16 + fr;
      af[f] = *(const f16x8*)&Ah[row * 32 + rchunk];
      const int col = wn + f * 16 + fr;
      bf[f] = *(const f16x8*)&Bh[col * 32 + rchunk];
    }
#pragma unroll
    for (int fa = 0; fa < 4; ++fa)
#pragma unroll
      for (int fb = 0; fb < 4; ++fb)
        acc[fa][fb] = __builtin_amdgcn_mfma_f32_16x16x32_f16(af[fa], bf[fb],
                                                             acc[fa][fb], 0, 0, 0);
  }

#pragma unroll
  for (int fb = 0; fb < 4; ++fb) {
    const int col = n0 + wn + fb * 16 + fr;
    const float bv = bias[col];
#pragma unroll
    for (int fa = 0; fa < 4; ++fa) {
#pragma unroll
      for (int r = 0; r < 4; ++r) {
        const int row = m0 + wm + fa * 16 + kg * 4 + r;
        _Float16 hv = (_Float16)(acc[fa][fb][r] + bv);
        Zl[(size_t)row * GATES + col] = *(const unsigned short*)&hv;
      }
    }
  }
}

/* ---------------- Phase 2: one time-step per launch ------------------------
 * The kernel-launch boundary IS the cross-block sync (hang-proof; no spin,
 * no co-residency assumption).  Block = (l, ug, jj): 128 seqs x 16 units x
 * 4 gates.  Grid 144*group; bid%8 = slab%8 pins each 49 KB weight slab to
 * one XCD, and all blocks sharing a slab run in the same launch window ->
 * slab is fetched once per step per XCD (this was the round-3 re-stream).
 * h (fp16) and c (fp32) round-trip through small L2/L3-resident buffers.
 * 4 waves; wave w = seqs [S0+w*32, +32) as 2 mfrags; nf = 4 gates; gates
 * are register-local per lane -> pointwise needs no exchange, 1 barrier. */
__global__ __launch_bounds__(256, 2) void recur_step(
    const unsigned short* __restrict__ Z,
    float* __restrict__ out,
    const unsigned short* __restrict__ Whg_,
    _Float16* __restrict__ hx,
    float* __restrict__ cbuf,
    int lbase, int group, int it) {
  const int bid = blockIdx.x;
  const int sx = bid & 7;
  const int q  = bid >> 3;
  const int nsl8 = 3 * group;
  const int shi = q % nsl8;
  const int jj  = q / nsl8;
  const int s   = shi * 8 + sx;          /* slab id 0..24*group-1 */
  const int l_local = s / 24;
  const int ug  = s % 24;
  const int l = lbase + l_local;
  const _Float16* __restrict__ Zl = (const _Float16*)Z + (size_t)l_local * NROWS * GATES;
  const int t = threadIdx.x;
  const int lane = t & 63;
  const int w = t >> 6;
  const int fr = lane & 15;
  const int kq = lane >> 4;
  const bool rev = (l & 1);
  const int S0 = jj * 128;
  const int uu = ug * 16 + fr;           /* absolute hidden unit */
  const int tt = rev ? (SEQT - 1 - it) : it;
  const int rstep = (l < 2) ? 1 : 24;

  __shared__ _Float16 WL[48 * 512];      /* 49152 B: [fi][lane][8] */

  /* ---- stage this step's weight slab (skipped at it=0: h==0) ---- */
  if (it) {
    const _Float16* wsrc = (const _Float16*)Whg_ + (size_t)(l * 24 + ug) * 24576;
#pragma unroll
    for (int i = 0; i < 12; ++i) {
      const int c16 = i * 256 + t;
      gl16(wsrc + (size_t)c16 * 8, WL + (size_t)c16 * 8);
    }
    __syncthreads();                     /* drains vmcnt: slab ready */
  }

  /* feature-row bases for this lane's 8 seqs: n = S0 + w*32 + mf*16 + kq*4 + r */
  int rb[2][4];
#pragma unroll
  for (int mf = 0; mf < 2; ++mf)
#pragma unroll
    for (int r = 0; r < 4; ++r) {
      const int n = S0 + w * 32 + mf * 16 + kq * 4 + r;
      rb[mf][r] = ((l < 2) ? n * SEQT : (n / 24) * 576 + (n % 24)) + tt * rstep;
    }

  /* Z prefetch (nt: single-use stream, keep out of L2) */
  _Float16 zv[2][4][4];
#pragma unroll
  for (int mf = 0; mf < 2; ++mf)
#pragma unroll
    for (int g = 0; g < 4; ++g)
#pragma unroll
      for (int r = 0; r < 4; ++r)
        zv[mf][g][r] = __builtin_nontemporal_load(
            Zl + (size_t)rb[mf][r] * GATES + g * 384 + uu);

  /* c(t-1) */
  float cv[2][4];
#pragma unroll
  for (int mf = 0; mf < 2; ++mf)
#pragma unroll
    for (int r = 0; r < 4; ++r) {
      const int n = S0 + w * 32 + mf * 16 + kq * 4 + r;
      cv[mf][r] = it ? cbuf[((size_t)l * NSEQ + n) * HID + uu] : 0.f;
    }

  f32x4 acc[2][4] = {};   /* [mf][g] */

  if (it) {
    const _Float16* hp = hx + ((size_t)(l * 2 + (it & 1)) * NSEQ) * HID;
    const _Float16* ha0 = hp + (size_t)(S0 + w * 32 + fr) * HID + kq * 8;
    const _Float16* ha1 = hp + (size_t)(S0 + w * 32 + 16 + fr) * HID + kq * 8;
    f16x8 a0 = *(const f16x8*)(ha0);
    f16x8 a1 = *(const f16x8*)(ha1);
#pragma unroll
    for (int kb = 0; kb < 12; ++kb) {
      const int kn = (kb < 11 ? kb + 1 : kb) * 32;
      const f16x8 n0 = *(const f16x8*)(ha0 + kn);
      const f16x8 n1 = *(const f16x8*)(ha1 + kn);
      f16x8 bfr[4];
#pragma unroll
      for (int g = 0; g < 4; ++g)
        bfr[g] = *(const f16x8*)&WL[((g * 12 + kb) * 64 + lane) * 8];
#pragma unroll
      for (int g = 0; g < 4; ++g) {
        acc[0][g] = __builtin_amdgcn_mfma_f32_16x16x32_f16(a0, bfr[g], acc[0][g], 0, 0, 0);
        acc[1][g] = __builtin_amdgcn_mfma_f32_16x16x32_f16(a1, bfr[g], acc[1][g], 0, 0, 0);
      }
      a0 = n0; a1 = n1;
    }
  }

  /* ---- pointwise LSTM + stores (gates register-local) ---- */
  _Float16* hw = hx + ((size_t)(l * 2 + ((it + 1) & 1)) * NSEQ) * HID + uu;
  float*    cw = cbuf + (size_t)l * NSEQ * HID + uu;
#pragma unroll
  for (int mf = 0; mf < 2; ++mf) {
#pragma unroll
    for (int r = 0; r < 4; ++r) {
      const int n = S0 + w * 32 + mf * 16 + kq * 4 + r;
      const float ig = fast_sigmoid(acc[mf][0][r] + (float)zv[mf][0][r]);
      const float fg = fast_sigmoid(acc[mf][1][r] + (float)zv[mf][1][r]);
      const float cd = fast_tanh  (acc[mf][2][r] + (float)zv[mf][2][r]);
      const float og = fast_sigmoid(acc[mf][3][r] + (float)zv[mf][3][r]);
      const float cn = fmaf(fg, cv[mf][r], ig * cd);
      const float hv = og * fast_tanh(cn);
      cw[(size_t)n * HID] = cn;
      hw[(size_t)n * HID] = (_Float16)hv;
      __builtin_nontemporal_store(hv, out + (size_t)rb[mf][r] * GATES + l * HID + uu);
    }
  }
}

extern "C" void kernel_launch(void* const* d_in, const int* in_sizes, int n_in,
                              void* d_out, int out_size, void* d_ws, size_t ws_size,
                              hipStream_t stream) {
  const float* feat = (const float*)d_in[0];
  WPtrs P;
  P.Wx[0] = (const float*)d_in[1];  P.Wh[0] = (const float*)d_in[2];  P.b[0] = (const float*)d_in[3];
  P.Wx[1] = (const float*)d_in[4];  P.Wh[1] = (const float*)d_in[5];  P.b[1] = (const float*)d_in[6];
  P.Wx[2] = (const float*)d_in[7];  P.Wh[2] = (const float*)d_in[8];  P.b[2] = (const float*)d_in[9];
  P.Wx[3] = (const float*)d_in[10]; P.Wh[3] = (const float*)d_in[11]; P.b[3] = (const float*)d_in[12];
  float* out = (float*)d_out;
  unsigned short* Z = (unsigned short*)d_ws;

  const size_t slabB = (size_t)NROWS * GATES * sizeof(unsigned short); /* 56.6 MB fp16 Z slab */
  const size_t xhB   = (size_t)NROWS * DIN * 2;                        /* 28.3 MB fp16 X */
  const size_t wxtB  = (size_t)4 * GATES * DIN * 2;                    /* 9.44 MB fp16 WxT */
  const size_t whgB  = (size_t)4 * 24 * 24576 * 2;                     /* 4.72 MB fp16 Whg */
  const size_t hxB   = (size_t)4 * 2 * NSEQ * HID * 2;                 /* 4.72 MB fp16 h dbuf */
  const size_t cbB   = (size_t)4 * NSEQ * HID * sizeof(float);         /* 4.72 MB fp32 c */
  const size_t extras = xhB + wxtB + whgB + hxB + cbB;
  const int group = (ws_size >= 4 * slabB + extras) ? 4
                  : (ws_size >= 2 * slabB + extras) ? 2 : 1;
  char* wp = (char*)d_ws + (size_t)group * slabB;
  unsigned short* Xh  = (unsigned short*)wp;  wp += xhB;
  unsigned short* WxT = (unsigned short*)wp;  wp += wxtB;
  unsigned short* Whg = (unsigned short*)wp;  wp += whgB;
  _Float16* hx        = (_Float16*)wp;        wp += hxB;
  float* cbuf         = (float*)wp;

  cvt_x<<<(NROWS * DIN / 4 + 255) / 256, 256, 0, stream>>>(feat, Xh);
  cvt_wx<<<dim3(GATES / 32, DIN / 32, 4), 256, 0, stream>>>(P, WxT);
  repack_whg<<<(4 * 24 * 48 * 64 + 255) / 256, 256, 0, stream>>>(P, Whg);

  for (int lbase = 0; lbase < 4; lbase += group) {
    gemm_zh<<<dim3(12 * group, NROWS / 128), 256, 0, stream>>>(Xh, WxT, P, lbase, Z);
    for (int it = 0; it < SEQT; ++it)
      recur_step<<<dim3(144 * group), 256, 0, stream>>>(Z, out, Whg, hx, cbuf,
                                                        lbase, group, it);
  }
}